// Round 10
// baseline (1330.220 us; speedup 1.0000x reference)
//
#include <hip/hip_runtime.h>
#include <hip/hip_fp16.h>
#include <hip/hip_cooperative_groups.h>

namespace cg = cooperative_groups;

// ---------------------------------------------------------------------------
// GIN, round 10: round-7 base (counting-sort CSR, f16 state, project-before-
// aggregate, fused projections) with the WHOLE network in ONE persistent
// cooperative kernel: weights staged to LDS once, grid.sync() between the 10
// aggregation rounds. Dispatches: 5 CSR + 1 network (was 15).
// ---------------------------------------------------------------------------

typedef unsigned int uint_t;

#define NBLK 256
#define NBMAX 400

struct alignas(16) H2x4 { __half2 x, y, z, w; };  // 8 f16 channels

static __device__ __forceinline__ float selu_f(float x) {
    const float scale = 1.0507009873554805f;
    const float alpha = 1.6732632423543772f;
    return x > 0.f ? scale * x : scale * alpha * (__expf(x) - 1.f);
}

static __device__ __forceinline__ int pb0(int v) {   // quad_perm [0,0,2,2]
    return __builtin_amdgcn_mov_dpp(v, 0xA0, 0xf, 0xf, true);
}
static __device__ __forceinline__ int pb1(int v) {   // quad_perm [1,1,3,3]
    return __builtin_amdgcn_mov_dpp(v, 0xF5, 0xf, 0xf, true);
}
static __device__ __forceinline__ float pswap(float x) {  // quad_perm [1,0,3,2]
    return __int_as_float(__builtin_amdgcn_mov_dpp(__float_as_int(x), 0xB1, 0xf, 0xf, true));
}

static __device__ __forceinline__ void acc_add(__half2& a0, __half2& a1,
                                               __half2& a2, __half2& a3, H2x4 v) {
    a0 = __hadd2(a0, v.x); a1 = __hadd2(a1, v.y);
    a2 = __hadd2(a2, v.z); a3 = __hadd2(a3, v.w);
}

// ============================ CSR build (round-7) ===========================

__global__ void k_hist(const int* __restrict__ dst, int* __restrict__ MT,
                       int e, int nb) {
    __shared__ int hist[NBMAX];
    for (int t = threadIdx.x; t < nb; t += 256) hist[t] = 0;
    __syncthreads();
    int chunk = (e + NBLK - 1) / NBLK;
    int lo = blockIdx.x * chunk, hi = min(e, lo + chunk);
    for (int i = lo + threadIdx.x; i < hi; i += 256)
        atomicAdd(&hist[dst[i] >> 8], 1);
    __syncthreads();
    for (int t = threadIdx.x; t < nb; t += 256)
        MT[t * NBLK + blockIdx.x] = hist[t];
}

__global__ void k_cscan(int* __restrict__ MT, int* __restrict__ tot, int nb) {
    int k = blockIdx.x;
    int lane = threadIdx.x;  // 64
    int carry = 0;
    #pragma unroll
    for (int r = 0; r < NBLK; r += 64) {
        int v = MT[k * NBLK + r + lane];
        int inc = v;
        #pragma unroll
        for (int d = 1; d < 64; d <<= 1) {
            int w = __shfl_up(inc, d, 64);
            if (lane >= d) inc += w;
        }
        MT[k * NBLK + r + lane] = carry + inc - v;
        carry += __shfl(inc, 63, 64);
    }
    if (lane == 0) tot[k] = carry;
}

__global__ void k_bscan(const int* __restrict__ tot, int* __restrict__ base,
                        int* __restrict__ rp, int nb, int e, int n) {
    __shared__ int s[512];
    int t = threadIdx.x;
    int v = (t < nb) ? tot[t] : 0;
    s[t] = v;
    __syncthreads();
    #pragma unroll
    for (int d = 1; d < 512; d <<= 1) {
        int w = (t >= d) ? s[t - d] : 0;
        __syncthreads();
        s[t] += w;
        __syncthreads();
    }
    if (t < nb) base[t] = s[t] - v;
    if (t == nb - 1) base[nb] = s[t];
    if (t == 0) rp[n] = e;
}

__global__ void k_scatter(const int* __restrict__ src, const int* __restrict__ dst,
                          const int* __restrict__ MT, const int* __restrict__ base,
                          uint_t* __restrict__ pairs, int e, int nb) {
    __shared__ int cur[NBMAX];
    for (int t = threadIdx.x; t < nb; t += 256)
        cur[t] = base[t] + MT[t * NBLK + blockIdx.x];
    __syncthreads();
    int chunk = (e + NBLK - 1) / NBLK;
    int lo = blockIdx.x * chunk, hi = min(e, lo + chunk);
    for (int i = lo + threadIdx.x; i < hi; i += 256) {
        int d = dst[i];
        int pos = atomicAdd(&cur[d >> 8], 1);
        pairs[pos] = (uint_t)src[i] | ((uint_t)(d & 255) << 24);
    }
}

__global__ void k_build(const uint_t* __restrict__ pairs, const int* __restrict__ base,
                        int* __restrict__ rp, int* __restrict__ esrc, int n) {
    int k = blockIdx.x;
    int bb = base[k], be = base[k + 1];
    __shared__ int cnt[256], cur[256], stmp[256];
    int t = threadIdx.x;
    cnt[t] = 0;
    __syncthreads();
    for (int i = bb + t; i < be; i += 256)
        atomicAdd(&cnt[pairs[i] >> 24], 1);
    __syncthreads();
    int v = cnt[t];
    stmp[t] = v;
    __syncthreads();
    #pragma unroll
    for (int d = 1; d < 256; d <<= 1) {
        int w = (t >= d) ? stmp[t - d] : 0;
        __syncthreads();
        stmp[t] += w;
        __syncthreads();
    }
    int excl = stmp[t] - v;
    int nd = k * 256 + t;
    if (nd < n) rp[nd] = bb + excl;
    cur[t] = bb + excl;
    __syncthreads();
    for (int i = bb + t; i < be; i += 256) {
        uint_t p = pairs[i];
        int pos = atomicAdd(&cur[p >> 24], 1);
        esrc[pos] = (int)(p & 0xFFFFFFu);
    }
}

// ===================== persistent cooperative network =======================
// sP0 layout: [0:16) W1_0 | [16:32) b1_0 | [32:544) W2_0 | [544:576) b2_0 |
//             [576:1088) W1m[0]
// sWnall[r*512 + ...]: r=0..6 -> W1m[r+1]; r=7 -> Wl (first 32 floats)

__global__ __launch_bounds__(256, 4) void k_net(
    const float* __restrict__ x,
    const int* __restrict__ rp, const int* __restrict__ esrc,
    const float* __restrict__ W1_0, const float* __restrict__ b1_0,
    const float* __restrict__ W2_0, const float* __restrict__ b2_0,
    const float* __restrict__ W1m, const float* __restrict__ b1m,
    const float* __restrict__ W2m, const float* __restrict__ b2m,
    const float* __restrict__ Wl,
    __half2* __restrict__ hP, __half2* __restrict__ hQ,
    __half2* __restrict__ gA, __half2* __restrict__ gB,
    float* __restrict__ z, float* __restrict__ out, int n) {
    cg::grid_group grid = cg::this_grid();

    __shared__ float sW2all[4096];   // W2m rounds 0..7
    __shared__ float sWnall[4096];   // next-proj weights per round
    __shared__ float sB1all[128], sB2all[256];
    __shared__ float sP0[1088];

    const int tid = threadIdx.x;
    for (int t = tid; t < 4096; t += 256) sW2all[t] = W2m[t];
    for (int t = tid; t < 3584; t += 256) sWnall[t] = W1m[512 + t];
    if (tid < 32) sWnall[3584 + tid] = Wl[tid];
    if (tid < 128) sB1all[tid] = b1m[tid];
    sB2all[tid] = b2m[tid];
    if (tid < 16) { sP0[tid] = W1_0[tid]; sP0[16 + tid] = b1_0[tid]; }
    for (int t = tid; t < 512; t += 256) { sP0[32 + t] = W2_0[t]; sP0[576 + t] = W1m[t]; }
    if (tid < 32) sP0[544 + tid] = b2_0[tid];
    __syncthreads();

    const int gtid = blockIdx.x * 256 + tid;
    const int gsize = gridDim.x * 256;

    // ---- phase 0: h1 = MLP0(agg(x)); g1 = h1 @ W1m[0] ----
    for (int i = gtid; i < n; i += gsize) {
        float a = x[i];
        int b = rp[i], en = rp[i + 1];
        int j = b;
        for (; j + 4 <= en; j += 4) {
            int s0 = esrc[j], s1 = esrc[j + 1], s2 = esrc[j + 2], s3 = esrc[j + 3];
            float v0 = x[s0], v1 = x[s1], v2 = x[s2], v3 = x[s3];
            a += (v0 + v1) + (v2 + v3);
        }
        for (; j < en; ++j) a += x[esrc[j]];
        float u[16];
        #pragma unroll
        for (int k = 0; k < 16; ++k) u[k] = selu_f(fmaf(a, sP0[k], sP0[16 + k]));
        float row[32];
        #pragma unroll
        for (int jj = 0; jj < 32; ++jj) {
            float acc = sP0[544 + jj];
            #pragma unroll
            for (int k = 0; k < 16; ++k) acc = fmaf(u[k], sP0[32 + k * 32 + jj], acc);
            row[jj] = acc;
        }
        H2x4* op = (H2x4*)hP + i * 4;
        #pragma unroll
        for (int q = 0; q < 4; ++q) {
            H2x4 vv;
            vv.x = __floats2half2_rn(row[q * 8 + 0], row[q * 8 + 1]);
            vv.y = __floats2half2_rn(row[q * 8 + 2], row[q * 8 + 3]);
            vv.z = __floats2half2_rn(row[q * 8 + 4], row[q * 8 + 5]);
            vv.w = __floats2half2_rn(row[q * 8 + 6], row[q * 8 + 7]);
            op[q] = vv;
        }
        float g[16];
        #pragma unroll
        for (int k = 0; k < 16; ++k) g[k] = 0.f;
        #pragma unroll
        for (int c = 0; c < 32; ++c) {
            float vc = row[c];
            #pragma unroll
            for (int k = 0; k < 16; ++k) g[k] = fmaf(vc, sP0[576 + c * 16 + k], g[k]);
        }
        H2x4* gp = (H2x4*)gA + i * 2;
        #pragma unroll
        for (int q = 0; q < 2; ++q) {
            H2x4 vv;
            vv.x = __floats2half2_rn(g[q * 8 + 0], g[q * 8 + 1]);
            vv.y = __floats2half2_rn(g[q * 8 + 2], g[q * 8 + 3]);
            vv.z = __floats2half2_rn(g[q * 8 + 4], g[q * 8 + 5]);
            vv.w = __floats2half2_rn(g[q * 8 + 6], g[q * 8 + 7]);
            gp[q] = vv;
        }
    }
    grid.sync();

    // ---- phases 1..8: gather(g) + MLP + residual (+ next proj / z) ----
    const __half2* gin = gA; const __half2* hin = hP;
    __half2* gout = gB;      __half2* hout = hQ;
    for (int r = 0; r < 8; ++r) {
        const float* sW2 = &sW2all[r * 512];
        const float* sWn = &sWnall[r * 512];
        const float* sb1 = &sB1all[r * 16];
        const float* sb2 = &sB2all[r * 32];
        const bool last = (r == 7);
        for (int t2 = gtid; t2 < 2 * n; t2 += gsize) {
            const int lane2 = t2 & 1;
            const int node = t2 >> 1;

            const H2x4* grows = (const H2x4*)gin;
            H2x4 a = grows[node * 2 + lane2];
            __half2 a0 = a.x, a1 = a.y, a2 = a.z, a3 = a.w;

            int b = rp[node];
            int deg = rp[node + 1] - b;
            int j0 = 0;
            for (; j0 + 8 <= deg; j0 += 8) {
                int e0 = esrc[b + j0 + lane2];
                int e1 = esrc[b + j0 + 2 + lane2];
                int e2 = esrc[b + j0 + 4 + lane2];
                int e3 = esrc[b + j0 + 6 + lane2];
                int s0 = pb0(e0), s1 = pb1(e0), s2 = pb0(e1), s3 = pb1(e1);
                int s4 = pb0(e2), s5 = pb1(e2), s6 = pb0(e3), s7 = pb1(e3);
                H2x4 v0 = grows[s0 * 2 + lane2];
                H2x4 v1 = grows[s1 * 2 + lane2];
                H2x4 v2 = grows[s2 * 2 + lane2];
                H2x4 v3 = grows[s3 * 2 + lane2];
                H2x4 v4 = grows[s4 * 2 + lane2];
                H2x4 v5 = grows[s5 * 2 + lane2];
                H2x4 v6 = grows[s6 * 2 + lane2];
                H2x4 v7 = grows[s7 * 2 + lane2];
                acc_add(a0, a1, a2, a3, v0);
                acc_add(a0, a1, a2, a3, v1);
                acc_add(a0, a1, a2, a3, v2);
                acc_add(a0, a1, a2, a3, v3);
                acc_add(a0, a1, a2, a3, v4);
                acc_add(a0, a1, a2, a3, v5);
                acc_add(a0, a1, a2, a3, v6);
                acc_add(a0, a1, a2, a3, v7);
            }
            for (; j0 < deg; ++j0) {
                int s = esrc[b + j0];
                H2x4 v = grows[s * 2 + lane2];
                acc_add(a0, a1, a2, a3, v);
            }

            float2 f0 = __half22float2(a0), f1 = __half22float2(a1),
                   f2 = __half22float2(a2), f3 = __half22float2(a3);
            float u[8] = {f0.x, f0.y, f1.x, f1.y, f2.x, f2.y, f3.x, f3.y};
            const int kb = lane2 * 8;
            #pragma unroll
            for (int q = 0; q < 8; ++q) u[q] = selu_f(u[q] + sb1[kb + q]);

            float ua[16];
            #pragma unroll
            for (int q = 0; q < 8; ++q) {
                float uo = pswap(u[q]);
                ua[q]     = lane2 ? uo   : u[q];
                ua[8 + q] = lane2 ? u[q] : uo;
            }

            const H2x4* hrows = (const H2x4*)hin;
            H2x4 h0 = hrows[node * 4 + lane2 * 2];
            H2x4 h1 = hrows[node * 4 + lane2 * 2 + 1];
            float hv[16];
            {
                float2 g0 = __half22float2(h0.x), g1 = __half22float2(h0.y),
                       g2 = __half22float2(h0.z), g3 = __half22float2(h0.w);
                float2 g4 = __half22float2(h1.x), g5 = __half22float2(h1.y),
                       g6 = __half22float2(h1.z), g7 = __half22float2(h1.w);
                hv[0] = g0.x; hv[1] = g0.y; hv[2] = g1.x; hv[3] = g1.y;
                hv[4] = g2.x; hv[5] = g2.y; hv[6] = g3.x; hv[7] = g3.y;
                hv[8] = g4.x; hv[9] = g4.y; hv[10] = g5.x; hv[11] = g5.y;
                hv[12] = g6.x; hv[13] = g6.y; hv[14] = g7.x; hv[15] = g7.y;
            }

            const int jb = lane2 * 16;
            float o[16];
            #pragma unroll
            for (int q = 0; q < 16; ++q) {
                float oo = sb2[jb + q];
                #pragma unroll
                for (int k = 0; k < 16; ++k) oo = fmaf(ua[k], sW2[k * 32 + jb + q], oo);
                o[q] = oo + hv[q];
            }

            if (!last) {
                H2x4 o0, o1;
                o0.x = __floats2half2_rn(o[0], o[1]);   o0.y = __floats2half2_rn(o[2], o[3]);
                o0.z = __floats2half2_rn(o[4], o[5]);   o0.w = __floats2half2_rn(o[6], o[7]);
                o1.x = __floats2half2_rn(o[8], o[9]);   o1.y = __floats2half2_rn(o[10], o[11]);
                o1.z = __floats2half2_rn(o[12], o[13]); o1.w = __floats2half2_rn(o[14], o[15]);
                ((H2x4*)hout)[node * 4 + lane2 * 2]     = o0;
                ((H2x4*)hout)[node * 4 + lane2 * 2 + 1] = o1;
                float gp[16];
                #pragma unroll
                for (int k = 0; k < 16; ++k) gp[k] = 0.f;
                #pragma unroll
                for (int q = 0; q < 16; ++q) {
                    float vc = o[q];
                    #pragma unroll
                    for (int k = 0; k < 16; ++k)
                        gp[k] = fmaf(vc, sWn[(jb + q) * 16 + k], gp[k]);
                }
                #pragma unroll
                for (int k = 0; k < 16; ++k) gp[k] += pswap(gp[k]);
                H2x4 gv;
                gv.x = __floats2half2_rn(gp[kb + 0], gp[kb + 1]);
                gv.y = __floats2half2_rn(gp[kb + 2], gp[kb + 3]);
                gv.z = __floats2half2_rn(gp[kb + 4], gp[kb + 5]);
                gv.w = __floats2half2_rn(gp[kb + 6], gp[kb + 7]);
                ((H2x4*)gout)[node * 2 + lane2] = gv;
            } else {
                float zp = 0.f;
                #pragma unroll
                for (int q = 0; q < 16; ++q) zp = fmaf(o[q], sWn[jb + q], zp);
                zp += pswap(zp);
                if (lane2 == 0) z[node] = zp;
            }
        }
        grid.sync();
        const __half2* tg = gin; gin = gout; gout = (__half2*)tg;
        const __half2* th = hin; hin = hout; hout = (__half2*)th;
    }

    // ---- phase 9: out = z + sum z[src] ----
    for (int i = gtid; i < n; i += gsize) {
        float acc = z[i];
        int b = rp[i], en = rp[i + 1];
        int j = b;
        for (; j + 4 <= en; j += 4) {
            int s0 = esrc[j], s1 = esrc[j + 1], s2 = esrc[j + 2], s3 = esrc[j + 3];
            float z0 = z[s0], z1 = z[s1], z2 = z[s2], z3 = z[s3];
            acc += (z0 + z1) + (z2 + z3);
        }
        for (; j < en; ++j) acc += z[esrc[j]];
        out[i] = acc;
    }
}

// ---------------------------------------------------------------------------

extern "C" void kernel_launch(void* const* d_in, const int* in_sizes, int n_in,
                              void* d_out, int out_size, void* d_ws, size_t ws_size,
                              hipStream_t stream) {
    const float* x    = (const float*)d_in[0];
    const int*   ei   = (const int*)d_in[1];
    const float* W1_0 = (const float*)d_in[2];
    const float* b1_0 = (const float*)d_in[3];
    const float* W2_0 = (const float*)d_in[4];
    const float* b2_0 = (const float*)d_in[5];
    const float* W1m  = (const float*)d_in[6];
    const float* b1m  = (const float*)d_in[7];
    const float* W2m  = (const float*)d_in[8];
    const float* b2m  = (const float*)d_in[9];
    const float* Wl   = (const float*)d_in[10];

    const int n = in_sizes[0];      // 100000 nodes
    const int e = in_sizes[1] / 2;  // 1.6M edges
    const int* srcp = ei;
    const int* dstp = ei + e;
    const int nb = (n + 255) >> 8;

    char* ws = (char*)d_ws;
    size_t off = 0;
    auto alloc = [&](size_t bytes) -> char* {
        char* p = ws + off;
        off += (bytes + 255) & ~size_t(255);
        return p;
    };
    __half2* hP   = (__half2*)alloc((size_t)n * 32 * 2);
    __half2* hQ   = (__half2*)alloc((size_t)n * 32 * 2);
    __half2* gA   = (__half2*)alloc((size_t)n * 16 * 2);
    __half2* gB   = (__half2*)alloc((size_t)n * 16 * 2);
    float*   z    = (float*)alloc((size_t)n * 4);
    int*     rp   = (int*)alloc((size_t)(n + 1) * 4);
    int*     esrc = (int*)alloc((size_t)e * 4);
    uint_t*  pairs= (uint_t*)alloc((size_t)e * 4);
    int*     MT   = (int*)alloc((size_t)NBMAX * NBLK * 4);
    int*     base = (int*)alloc((size_t)(NBMAX + 1) * 4);
    int*     tot  = (int*)alloc((size_t)NBMAX * 4);
    (void)ws_size;

    const int B = 256;

    // --- CSR build ---
    k_hist<<<NBLK, B, 0, stream>>>(dstp, MT, e, nb);
    k_cscan<<<nb, 64, 0, stream>>>(MT, tot, nb);
    k_bscan<<<1, 512, 0, stream>>>(tot, base, rp, nb, e, n);
    k_scatter<<<NBLK, B, 0, stream>>>(srcp, dstp, MT, base, pairs, e, nb);
    k_build<<<nb, B, 0, stream>>>(pairs, base, rp, esrc, n);

    // --- whole network: one cooperative kernel ---
    int dev = 0;
    hipGetDevice(&dev);
    int numCU = 256;
    hipDeviceGetAttribute(&numCU, hipDeviceAttributeMultiprocessorCount, dev);
    int maxB = 0;
    if (hipOccupancyMaxActiveBlocksPerMultiprocessor(&maxB, (const void*)k_net, B, 0)
        != hipSuccess || maxB < 1)
        maxB = 1;
    int needed = (2 * n + B - 1) / B;          // widest phase: 2 lanes/node
    int gridN = maxB * numCU;
    if (needed < gridN) gridN = needed;

    float* outp = (float*)d_out;
    int nn = n;
    void* args[] = {
        (void*)&x, (void*)&rp, (void*)&esrc,
        (void*)&W1_0, (void*)&b1_0, (void*)&W2_0, (void*)&b2_0,
        (void*)&W1m, (void*)&b1m, (void*)&W2m, (void*)&b2m, (void*)&Wl,
        (void*)&hP, (void*)&hQ, (void*)&gA, (void*)&gB,
        (void*)&z, (void*)&outp, (void*)&nn
    };
    hipLaunchCooperativeKernel((void*)k_net, dim3(gridN), dim3(B), args, 0, stream);
}

// Round 12
// 252.121 us; speedup vs baseline: 5.2761x; 5.2761x over previous
//
#include <hip/hip_runtime.h>
#include <hip/hip_fp16.h>

// ---------------------------------------------------------------------------
// GIN, round 12 (= round 11 with pad-row memset offset fixed): round-7 base
// (counting-sort CSR, f16 state, project-before-aggregate, fused projections)
// + TLP doubling in the gather kernels:
//   k_gmid: 4 lanes/node — lane-pairs split the edge list (16-edge chunks),
//           pair-local DPP broadcasts, one xor2 exchange to combine; MLP
//           splits output channels 4 ways; masked tail loads hit a zero pad
//           row (row n, byte offset n*32). float4 LDS weight reads.
//   k_b0g/k_gz: 2 lanes/node, edge list halved per lane, pswap combine.
// ---------------------------------------------------------------------------

typedef unsigned int uint_t;

#define NBLK 256
#define NBMAX 400

struct alignas(16) H2x4 { __half2 x, y, z, w; };  // 8 f16 channels
struct alignas(8)  H2x2 { __half2 x, y; };        // 4 f16 channels

static __device__ __forceinline__ float selu_f(float x) {
    const float scale = 1.0507009873554805f;
    const float alpha = 1.6732632423543772f;
    return x > 0.f ? scale * x : scale * alpha * (__expf(x) - 1.f);
}

// quad_perm DPP helpers
static __device__ __forceinline__ int pb0(int v) {   // [0,0,2,2] pair-bcast even
    return __builtin_amdgcn_mov_dpp(v, 0xA0, 0xf, 0xf, true);
}
static __device__ __forceinline__ int pb1(int v) {   // [1,1,3,3] pair-bcast odd
    return __builtin_amdgcn_mov_dpp(v, 0xF5, 0xf, 0xf, true);
}
static __device__ __forceinline__ float pswap(float x) {  // [1,0,3,2] pair swap
    return __int_as_float(__builtin_amdgcn_mov_dpp(__float_as_int(x), 0xB1, 0xf, 0xf, true));
}
static __device__ __forceinline__ float qx2f(float x) {   // [2,3,0,1] xor-2 swap
    return __int_as_float(__builtin_amdgcn_mov_dpp(__float_as_int(x), 0x4E, 0xf, 0xf, true));
}
static __device__ __forceinline__ __half2 h2qx2(__half2 v) {
    int i; __builtin_memcpy(&i, &v, 4);
    i = __builtin_amdgcn_mov_dpp(i, 0x4E, 0xf, 0xf, true);
    __half2 r; __builtin_memcpy(&r, &i, 4);
    return r;
}

static __device__ __forceinline__ void acc_add(__half2& a0, __half2& a1,
                                               __half2& a2, __half2& a3, H2x4 v) {
    a0 = __hadd2(a0, v.x); a1 = __hadd2(a1, v.y);
    a2 = __hadd2(a2, v.z); a3 = __hadd2(a3, v.w);
}

// ============================ CSR build (round-7) ===========================

__global__ void k_hist(const int* __restrict__ dst, int* __restrict__ MT,
                       int e, int nb) {
    __shared__ int hist[NBMAX];
    for (int t = threadIdx.x; t < nb; t += 256) hist[t] = 0;
    __syncthreads();
    int chunk = (e + NBLK - 1) / NBLK;
    int lo = blockIdx.x * chunk, hi = min(e, lo + chunk);
    for (int i = lo + threadIdx.x; i < hi; i += 256)
        atomicAdd(&hist[dst[i] >> 8], 1);
    __syncthreads();
    for (int t = threadIdx.x; t < nb; t += 256)
        MT[t * NBLK + blockIdx.x] = hist[t];
}

__global__ void k_cscan(int* __restrict__ MT, int* __restrict__ tot, int nb) {
    int k = blockIdx.x;
    int lane = threadIdx.x;  // 64
    int carry = 0;
    #pragma unroll
    for (int r = 0; r < NBLK; r += 64) {
        int v = MT[k * NBLK + r + lane];
        int inc = v;
        #pragma unroll
        for (int d = 1; d < 64; d <<= 1) {
            int w = __shfl_up(inc, d, 64);
            if (lane >= d) inc += w;
        }
        MT[k * NBLK + r + lane] = carry + inc - v;
        carry += __shfl(inc, 63, 64);
    }
    if (lane == 0) tot[k] = carry;
}

__global__ void k_bscan(const int* __restrict__ tot, int* __restrict__ base,
                        int* __restrict__ rp, int nb, int e, int n) {
    __shared__ int s[512];
    int t = threadIdx.x;
    int v = (t < nb) ? tot[t] : 0;
    s[t] = v;
    __syncthreads();
    #pragma unroll
    for (int d = 1; d < 512; d <<= 1) {
        int w = (t >= d) ? s[t - d] : 0;
        __syncthreads();
        s[t] += w;
        __syncthreads();
    }
    if (t < nb) base[t] = s[t] - v;
    if (t == nb - 1) base[nb] = s[t];
    if (t == 0) rp[n] = e;
}

__global__ void k_scatter(const int* __restrict__ src, const int* __restrict__ dst,
                          const int* __restrict__ MT, const int* __restrict__ base,
                          uint_t* __restrict__ pairs, int e, int nb) {
    __shared__ int cur[NBMAX];
    for (int t = threadIdx.x; t < nb; t += 256)
        cur[t] = base[t] + MT[t * NBLK + blockIdx.x];
    __syncthreads();
    int chunk = (e + NBLK - 1) / NBLK;
    int lo = blockIdx.x * chunk, hi = min(e, lo + chunk);
    for (int i = lo + threadIdx.x; i < hi; i += 256) {
        int d = dst[i];
        int pos = atomicAdd(&cur[d >> 8], 1);
        pairs[pos] = (uint_t)src[i] | ((uint_t)(d & 255) << 24);
    }
}

__global__ void k_build(const uint_t* __restrict__ pairs, const int* __restrict__ base,
                        int* __restrict__ rp, int* __restrict__ esrc, int n) {
    int k = blockIdx.x;
    int bb = base[k], be = base[k + 1];
    __shared__ int cnt[256], cur[256], stmp[256];
    int t = threadIdx.x;
    cnt[t] = 0;
    __syncthreads();
    for (int i = bb + t; i < be; i += 256)
        atomicAdd(&cnt[pairs[i] >> 24], 1);
    __syncthreads();
    int v = cnt[t];
    stmp[t] = v;
    __syncthreads();
    #pragma unroll
    for (int d = 1; d < 256; d <<= 1) {
        int w = (t >= d) ? stmp[t - d] : 0;
        __syncthreads();
        stmp[t] += w;
        __syncthreads();
    }
    int excl = stmp[t] - v;
    int nd = k * 256 + t;
    if (nd < n) rp[nd] = bb + excl;
    cur[t] = bb + excl;
    __syncthreads();
    for (int i = bb + t; i < be; i += 256) {
        uint_t p = pairs[i];
        int pos = atomicAdd(&cur[p >> 24], 1);
        esrc[pos] = (int)(p & 0xFFFFFFu);
    }
}

// ============================ network kernels ===============================

// block 0: 2 lanes/node. Edge list halved per lane; MLP output split 16/16.
__global__ __launch_bounds__(256) void k_b0g(
    const float* __restrict__ x, const int* __restrict__ rp,
    const int* __restrict__ esrc,
    const float* __restrict__ W1, const float* __restrict__ b1,
    const float* __restrict__ W2, const float* __restrict__ b2,
    const float* __restrict__ W1next,
    __half2* __restrict__ hout, __half2* __restrict__ gout, int n) {
    __shared__ __align__(16) float sW1[16], sb1v[16], sW2[512], sb2v[32], sWn[512];
    if (threadIdx.x < 16) { sW1[threadIdx.x] = W1[threadIdx.x]; sb1v[threadIdx.x] = b1[threadIdx.x]; }
    for (int t = threadIdx.x; t < 512; t += 256) { sW2[t] = W2[t]; sWn[t] = W1next[t]; }
    if (threadIdx.x < 32) sb2v[threadIdx.x] = b2[threadIdx.x];
    __syncthreads();
    const int lane2 = threadIdx.x & 1;
    const int node = blockIdx.x * 128 + (threadIdx.x >> 1);
    if (node >= n) return;

    const int b = rp[node];
    const int deg = rp[node + 1] - b;
    const int half = deg >> 1;
    const int lo = lane2 ? half : 0;
    const int hi = lane2 ? deg : half;
    float a = lane2 ? 0.f : x[node];
    int j = lo;
    for (; j + 4 <= hi; j += 4) {
        int s0 = esrc[b + j], s1 = esrc[b + j + 1],
            s2 = esrc[b + j + 2], s3 = esrc[b + j + 3];
        float v0 = x[s0], v1 = x[s1], v2 = x[s2], v3 = x[s3];
        a += (v0 + v1) + (v2 + v3);
    }
    for (; j < hi; ++j) a += x[esrc[b + j]];
    a += pswap(a);   // both lanes hold full aggregate

    float u[16];
    #pragma unroll
    for (int k = 0; k < 16; ++k) u[k] = selu_f(fmaf(a, sW1[k], sb1v[k]));

    const int jb = lane2 * 16;
    float row[16];
    #pragma unroll
    for (int q = 0; q < 16; ++q) row[q] = sb2v[jb + q];
    #pragma unroll
    for (int k = 0; k < 16; ++k) {
        const float4 w0 = *(const float4*)&sW2[k * 32 + jb];
        const float4 w1 = *(const float4*)&sW2[k * 32 + jb + 4];
        const float4 w2 = *(const float4*)&sW2[k * 32 + jb + 8];
        const float4 w3 = *(const float4*)&sW2[k * 32 + jb + 12];
        float uk = u[k];
        row[0]  = fmaf(uk, w0.x, row[0]);  row[1]  = fmaf(uk, w0.y, row[1]);
        row[2]  = fmaf(uk, w0.z, row[2]);  row[3]  = fmaf(uk, w0.w, row[3]);
        row[4]  = fmaf(uk, w1.x, row[4]);  row[5]  = fmaf(uk, w1.y, row[5]);
        row[6]  = fmaf(uk, w1.z, row[6]);  row[7]  = fmaf(uk, w1.w, row[7]);
        row[8]  = fmaf(uk, w2.x, row[8]);  row[9]  = fmaf(uk, w2.y, row[9]);
        row[10] = fmaf(uk, w2.z, row[10]); row[11] = fmaf(uk, w2.w, row[11]);
        row[12] = fmaf(uk, w3.x, row[12]); row[13] = fmaf(uk, w3.y, row[13]);
        row[14] = fmaf(uk, w3.z, row[14]); row[15] = fmaf(uk, w3.w, row[15]);
    }
    H2x4 o0, o1;
    o0.x = __floats2half2_rn(row[0], row[1]);   o0.y = __floats2half2_rn(row[2], row[3]);
    o0.z = __floats2half2_rn(row[4], row[5]);   o0.w = __floats2half2_rn(row[6], row[7]);
    o1.x = __floats2half2_rn(row[8], row[9]);   o1.y = __floats2half2_rn(row[10], row[11]);
    o1.z = __floats2half2_rn(row[12], row[13]); o1.w = __floats2half2_rn(row[14], row[15]);
    ((H2x4*)hout)[node * 4 + lane2 * 2]     = o0;
    ((H2x4*)hout)[node * 4 + lane2 * 2 + 1] = o1;

    // fused projection partial over own 16 h-channels, then pair reduce
    float gp[16];
    #pragma unroll
    for (int k = 0; k < 16; ++k) gp[k] = 0.f;
    #pragma unroll
    for (int q = 0; q < 16; ++q) {
        const float4 w0 = *(const float4*)&sWn[(jb + q) * 16];
        const float4 w1 = *(const float4*)&sWn[(jb + q) * 16 + 4];
        const float4 w2 = *(const float4*)&sWn[(jb + q) * 16 + 8];
        const float4 w3 = *(const float4*)&sWn[(jb + q) * 16 + 12];
        float vq = row[q];
        gp[0]  = fmaf(vq, w0.x, gp[0]);  gp[1]  = fmaf(vq, w0.y, gp[1]);
        gp[2]  = fmaf(vq, w0.z, gp[2]);  gp[3]  = fmaf(vq, w0.w, gp[3]);
        gp[4]  = fmaf(vq, w1.x, gp[4]);  gp[5]  = fmaf(vq, w1.y, gp[5]);
        gp[6]  = fmaf(vq, w1.z, gp[6]);  gp[7]  = fmaf(vq, w1.w, gp[7]);
        gp[8]  = fmaf(vq, w2.x, gp[8]);  gp[9]  = fmaf(vq, w2.y, gp[9]);
        gp[10] = fmaf(vq, w2.z, gp[10]); gp[11] = fmaf(vq, w2.w, gp[11]);
        gp[12] = fmaf(vq, w3.x, gp[12]); gp[13] = fmaf(vq, w3.y, gp[13]);
        gp[14] = fmaf(vq, w3.z, gp[14]); gp[15] = fmaf(vq, w3.w, gp[15]);
    }
    float r[8];
    #pragma unroll
    for (int i = 0; i < 8; ++i) {
        float lo_ = gp[i]     + pswap(gp[i]);
        float hi_ = gp[8 + i] + pswap(gp[8 + i]);
        r[i] = lane2 ? hi_ : lo_;
    }
    H2x4 gv;
    gv.x = __floats2half2_rn(r[0], r[1]); gv.y = __floats2half2_rn(r[2], r[3]);
    gv.z = __floats2half2_rn(r[4], r[5]); gv.w = __floats2half2_rn(r[6], r[7]);
    ((H2x4*)gout)[node * 2 + lane2] = gv;
}

// mid blocks: 4 lanes/node. c = column half of g row, p = edge-chunk half.
template<int MODE>
__global__ __launch_bounds__(256, 4) void k_gmid(
    const __half2* __restrict__ gin, const __half2* __restrict__ hin,
    const int* __restrict__ rp, const int* __restrict__ esrc,
    const float* __restrict__ W2, const float* __restrict__ b1,
    const float* __restrict__ b2, const float* __restrict__ Wnext,
    __half2* __restrict__ hout, __half2* __restrict__ gout,
    float* __restrict__ zout, int n) {
    __shared__ __align__(16) float sW2[512], sb1[16], sb2[32], sWn[512];
    for (int t = threadIdx.x; t < 512; t += 256) sW2[t] = W2[t];
    if (MODE == 0) {
        for (int t = threadIdx.x; t < 512; t += 256) sWn[t] = Wnext[t];
    } else {
        if (threadIdx.x < 32) sWn[threadIdx.x] = Wnext[threadIdx.x];
    }
    if (threadIdx.x < 16) sb1[threadIdx.x] = b1[threadIdx.x];
    else if (threadIdx.x < 48) sb2[threadIdx.x - 16] = b2[threadIdx.x - 16];
    __syncthreads();

    const int lane4 = threadIdx.x & 3;
    const int c = lane4 & 1;       // which 16B half of the 32B g row
    const int p = lane4 >> 1;      // which 8-edge sub-chunk of each 16
    const int node = blockIdx.x * 64 + (threadIdx.x >> 2);
    if (node >= n) return;

    const H2x4* grows = (const H2x4*)gin;
    H2x4 self = grows[node * 2 + c];
    __half2 hzero = __floats2half2_rn(0.f, 0.f);
    __half2 a0 = p ? hzero : self.x, a1 = p ? hzero : self.y,
            a2 = p ? hzero : self.z, a3 = p ? hzero : self.w;

    const int b = rp[node];
    const int deg = rp[node + 1] - b;
    const int ZR = n;   // zero pad row (memset at launch)
    for (int j0 = 0; j0 < deg; j0 += 16) {
        int lo = j0 + 8 * p;
        int m = deg - lo; m = m < 0 ? 0 : (m > 8 ? 8 : m);
        int i0 = lo + c,     i1 = lo + 2 + c, i2 = lo + 4 + c, i3 = lo + 6 + c;
        i0 = i0 < deg ? i0 : 0; i1 = i1 < deg ? i1 : 0;
        i2 = i2 < deg ? i2 : 0; i3 = i3 < deg ? i3 : 0;
        int e0 = esrc[b + i0], e1 = esrc[b + i1], e2 = esrc[b + i2], e3 = esrc[b + i3];
        int s0 = pb0(e0), s1 = pb1(e0), s2 = pb0(e1), s3 = pb1(e1);
        int s4 = pb0(e2), s5 = pb1(e2), s6 = pb0(e3), s7 = pb1(e3);
        s0 = 0 < m ? s0 : ZR; s1 = 1 < m ? s1 : ZR;
        s2 = 2 < m ? s2 : ZR; s3 = 3 < m ? s3 : ZR;
        s4 = 4 < m ? s4 : ZR; s5 = 5 < m ? s5 : ZR;
        s6 = 6 < m ? s6 : ZR; s7 = 7 < m ? s7 : ZR;
        H2x4 v0 = grows[s0 * 2 + c];
        H2x4 v1 = grows[s1 * 2 + c];
        H2x4 v2 = grows[s2 * 2 + c];
        H2x4 v3 = grows[s3 * 2 + c];
        H2x4 v4 = grows[s4 * 2 + c];
        H2x4 v5 = grows[s5 * 2 + c];
        H2x4 v6 = grows[s6 * 2 + c];
        H2x4 v7 = grows[s7 * 2 + c];
        acc_add(a0, a1, a2, a3, v0);
        acc_add(a0, a1, a2, a3, v1);
        acc_add(a0, a1, a2, a3, v2);
        acc_add(a0, a1, a2, a3, v3);
        acc_add(a0, a1, a2, a3, v4);
        acc_add(a0, a1, a2, a3, v5);
        acc_add(a0, a1, a2, a3, v6);
        acc_add(a0, a1, a2, a3, v7);
    }
    // combine the two edge-half partials (lane xor 2)
    a0 = __hadd2(a0, h2qx2(a0)); a1 = __hadd2(a1, h2qx2(a1));
    a2 = __hadd2(a2, h2qx2(a2)); a3 = __hadd2(a3, h2qx2(a3));

    float2 f0 = __half22float2(a0), f1 = __half22float2(a1),
           f2 = __half22float2(a2), f3 = __half22float2(a3);
    float u[8] = {f0.x, f0.y, f1.x, f1.y, f2.x, f2.y, f3.x, f3.y};
    const int kb = c * 8;
    #pragma unroll
    for (int q = 0; q < 8; ++q) u[q] = selu_f(u[q] + sb1[kb + q]);

    float ua[16];
    #pragma unroll
    for (int q = 0; q < 8; ++q) {
        float uo = pswap(u[q]);
        ua[q]     = c ? uo   : u[q];
        ua[8 + q] = c ? u[q] : uo;
    }

    const int jb = lane4 * 8;   // this lane's 8 output channels
    const H2x4* hrows = (const H2x4*)hin;
    H2x4 h0 = hrows[node * 4 + lane4];
    float2 g0 = __half22float2(h0.x), g1 = __half22float2(h0.y),
           g2 = __half22float2(h0.z), g3 = __half22float2(h0.w);
    float o[8] = {g0.x, g0.y, g1.x, g1.y, g2.x, g2.y, g3.x, g3.y};  // residual
    #pragma unroll
    for (int q = 0; q < 8; ++q) o[q] += sb2[jb + q];
    #pragma unroll
    for (int k = 0; k < 16; ++k) {
        const float4 w0 = *(const float4*)&sW2[k * 32 + jb];
        const float4 w1 = *(const float4*)&sW2[k * 32 + jb + 4];
        float uk = ua[k];
        o[0] = fmaf(uk, w0.x, o[0]); o[1] = fmaf(uk, w0.y, o[1]);
        o[2] = fmaf(uk, w0.z, o[2]); o[3] = fmaf(uk, w0.w, o[3]);
        o[4] = fmaf(uk, w1.x, o[4]); o[5] = fmaf(uk, w1.y, o[5]);
        o[6] = fmaf(uk, w1.z, o[6]); o[7] = fmaf(uk, w1.w, o[7]);
    }

    if (MODE == 0) {
        H2x4 ov;
        ov.x = __floats2half2_rn(o[0], o[1]); ov.y = __floats2half2_rn(o[2], o[3]);
        ov.z = __floats2half2_rn(o[4], o[5]); ov.w = __floats2half2_rn(o[6], o[7]);
        ((H2x4*)hout)[node * 4 + lane4] = ov;

        float gp[16];
        #pragma unroll
        for (int k = 0; k < 16; ++k) gp[k] = 0.f;
        #pragma unroll
        for (int q = 0; q < 8; ++q) {
            const float4 w0 = *(const float4*)&sWn[(jb + q) * 16];
            const float4 w1 = *(const float4*)&sWn[(jb + q) * 16 + 4];
            const float4 w2 = *(const float4*)&sWn[(jb + q) * 16 + 8];
            const float4 w3 = *(const float4*)&sWn[(jb + q) * 16 + 12];
            float vq = o[q];
            gp[0]  = fmaf(vq, w0.x, gp[0]);  gp[1]  = fmaf(vq, w0.y, gp[1]);
            gp[2]  = fmaf(vq, w0.z, gp[2]);  gp[3]  = fmaf(vq, w0.w, gp[3]);
            gp[4]  = fmaf(vq, w1.x, gp[4]);  gp[5]  = fmaf(vq, w1.y, gp[5]);
            gp[6]  = fmaf(vq, w1.z, gp[6]);  gp[7]  = fmaf(vq, w1.w, gp[7]);
            gp[8]  = fmaf(vq, w2.x, gp[8]);  gp[9]  = fmaf(vq, w2.y, gp[9]);
            gp[10] = fmaf(vq, w2.z, gp[10]); gp[11] = fmaf(vq, w2.w, gp[11]);
            gp[12] = fmaf(vq, w3.x, gp[12]); gp[13] = fmaf(vq, w3.y, gp[13]);
            gp[14] = fmaf(vq, w3.z, gp[14]); gp[15] = fmaf(vq, w3.w, gp[15]);
        }
        // distributed quad reduce: stage 1 pair (keep c-half), stage 2 xor2
        // (keep p-quarter); lane ends with channels [c*8 + p*4, +4)
        float r[8];
        #pragma unroll
        for (int i = 0; i < 8; ++i) {
            float lo_ = gp[i]     + pswap(gp[i]);
            float hi_ = gp[8 + i] + pswap(gp[8 + i]);
            r[i] = c ? hi_ : lo_;
        }
        float rr[4];
        #pragma unroll
        for (int i = 0; i < 4; ++i) {
            float lo_ = r[i]     + qx2f(r[i]);
            float hi_ = r[4 + i] + qx2f(r[4 + i]);
            rr[i] = p ? hi_ : lo_;
        }
        H2x2 gv;
        gv.x = __floats2half2_rn(rr[0], rr[1]);
        gv.y = __floats2half2_rn(rr[2], rr[3]);
        ((H2x2*)gout)[node * 4 + c * 2 + p] = gv;
    } else {
        float zp = 0.f;
        #pragma unroll
        for (int q = 0; q < 8; ++q) zp = fmaf(o[q], sWn[jb + q], zp);
        zp += pswap(zp);
        zp += qx2f(zp);
        if (lane4 == 0) zout[node] = zp;
    }
}

// last gather: 2 lanes/node, halved edge list
__global__ void k_gz(const float* __restrict__ z, const int* __restrict__ rp,
                     const int* __restrict__ esrc, float* __restrict__ out, int n) {
    const int lane2 = threadIdx.x & 1;
    const int node = blockIdx.x * 128 + (threadIdx.x >> 1);
    if (node >= n) return;
    const int b = rp[node];
    const int deg = rp[node + 1] - b;
    const int half = deg >> 1;
    const int lo = lane2 ? half : 0;
    const int hi = lane2 ? deg : half;
    float acc = lane2 ? 0.f : z[node];
    int j = lo;
    for (; j + 4 <= hi; j += 4) {
        int s0 = esrc[b + j], s1 = esrc[b + j + 1],
            s2 = esrc[b + j + 2], s3 = esrc[b + j + 3];
        float z0 = z[s0], z1 = z[s1], z2 = z[s2], z3 = z[s3];
        acc += (z0 + z1) + (z2 + z3);
    }
    for (; j < hi; ++j) acc += z[esrc[b + j]];
    acc += pswap(acc);
    if (lane2 == 0) out[node] = acc;
}

// ---------------------------------------------------------------------------

extern "C" void kernel_launch(void* const* d_in, const int* in_sizes, int n_in,
                              void* d_out, int out_size, void* d_ws, size_t ws_size,
                              hipStream_t stream) {
    const float* x    = (const float*)d_in[0];
    const int*   ei   = (const int*)d_in[1];
    const float* W1_0 = (const float*)d_in[2];
    const float* b1_0 = (const float*)d_in[3];
    const float* W2_0 = (const float*)d_in[4];
    const float* b2_0 = (const float*)d_in[5];
    const float* W1m  = (const float*)d_in[6];
    const float* b1m  = (const float*)d_in[7];
    const float* W2m  = (const float*)d_in[8];
    const float* b2m  = (const float*)d_in[9];
    const float* Wl   = (const float*)d_in[10];

    const int n = in_sizes[0];      // 100000 nodes
    const int e = in_sizes[1] / 2;  // 1.6M edges
    const int* srcp = ei;
    const int* dstp = ei + e;
    const int nb = (n + 255) >> 8;

    char* ws = (char*)d_ws;
    size_t off = 0;
    auto alloc = [&](size_t bytes) -> char* {
        char* p = ws + off;
        off += (bytes + 255) & ~size_t(255);
        return p;
    };
    __half2* hP   = (__half2*)alloc((size_t)n * 32 * 2);
    __half2* hQ   = (__half2*)alloc((size_t)n * 32 * 2);
    __half2* gA   = (__half2*)alloc((size_t)(n + 1) * 16 * 2);  // +1 zero pad row
    __half2* gB   = (__half2*)alloc((size_t)(n + 1) * 16 * 2);
    float*   z    = (float*)alloc((size_t)n * 4);
    int*     rp   = (int*)alloc((size_t)(n + 1) * 4);
    int*     esrc = (int*)alloc((size_t)e * 4);
    uint_t*  pairs= (uint_t*)alloc((size_t)e * 4);
    int*     MT   = (int*)alloc((size_t)NBMAX * NBLK * 4);
    int*     base = (int*)alloc((size_t)(NBMAX + 1) * 4);
    int*     tot  = (int*)alloc((size_t)NBMAX * 4);
    (void)ws_size;

    const int B = 256;
    const int gN = (n + B - 1) / B;
    const int g2 = (n + 127) / 128;   // 2 lanes/node kernels
    const int g4 = (n + 63) / 64;     // 4 lanes/node kernels

    // zero the pad rows (row n of gA/gB): row = 16 f16 = 8 __half2 = 32 bytes.
    // Pad row starts at element offset n*8 (FIXED: was n*16 = byte offset n*64,
    // out of region — left pad poisoned AND corrupted the next buffer).
    hipMemsetAsync(gA + (size_t)n * 8, 0, 32, stream);
    hipMemsetAsync(gB + (size_t)n * 8, 0, 32, stream);

    // --- CSR build ---
    k_hist<<<NBLK, B, 0, stream>>>(dstp, MT, e, nb);
    k_cscan<<<nb, 64, 0, stream>>>(MT, tot, nb);
    k_bscan<<<1, 512, 0, stream>>>(tot, base, rp, nb, e, n);
    k_scatter<<<NBLK, B, 0, stream>>>(srcp, dstp, MT, base, pairs, e, nb);
    k_build<<<nb, B, 0, stream>>>(pairs, base, rp, esrc, n);

    // --- block 0 (+ fused g1) ---
    k_b0g<<<g2, B, 0, stream>>>(x, rp, esrc, W1_0, b1_0, W2_0, b2_0,
                                W1m /* W1[0] */, hP, gA, n);

    // --- blocks 1..8 ---
    __half2* A = hP;  __half2* Bf = hQ;
    __half2* gin = gA; __half2* gnx = gB;
    for (int i = 0; i < 8; ++i) {
        if (i < 7) {
            k_gmid<0><<<g4, B, 0, stream>>>(gin, A, rp, esrc,
                                            W2m + i * 512, b1m + i * 16,
                                            b2m + i * 32, W1m + (i + 1) * 512,
                                            Bf, gnx, nullptr, n);
        } else {
            k_gmid<1><<<g4, B, 0, stream>>>(gin, A, rp, esrc,
                                            W2m + i * 512, b1m + i * 16,
                                            b2m + i * 32, Wl,
                                            Bf, nullptr, z, n);
        }
        __half2* t = A; A = Bf; Bf = t;
        __half2* tg = gin; gin = gnx; gnx = tg;
    }

    // --- block 9: gather of z ---
    k_gz<<<g2, B, 0, stream>>>(z, rp, esrc, (float*)d_out, n);
}

// Round 13
// 237.236 us; speedup vs baseline: 5.6072x; 1.0627x over previous
//
#include <hip/hip_runtime.h>
#include <hip/hip_fp16.h>

// ---------------------------------------------------------------------------
// GIN, round 13: round-12 base + k_gmid register-diet for the 64-VGPR
// occupancy cliff (waves/CU steps at VGPR=64/128/256 on gfx950):
//   - W2 / W1next staged in LDS as packed f16 pairs; MLP + fused projection
//     via v_dot2_f32_f16 (f32 accumulate) -> ua[16]+float4 temps eliminated.
//   - __launch_bounds__(256, 8) to force allocation <= 64 VGPR.
//   - accumulator init by index-selecting the zero pad row (no self/select).
// Gather loop, CSR build, k_b0g, k_gz unchanged from round 12 (passing).
// ---------------------------------------------------------------------------

typedef unsigned int uint_t;

#define NBLK 256
#define NBMAX 400

struct alignas(16) H2x4 { __half2 x, y, z, w; };  // 8 f16 channels
struct alignas(8)  H2x2 { __half2 x, y; };        // 4 f16 channels

#if defined(__has_builtin)
#if __has_builtin(__builtin_amdgcn_fdot2)
#define HAS_FDOT2 1
#endif
#endif

typedef _Float16 half2v __attribute__((ext_vector_type(2)));

static __device__ __forceinline__ float dot2(__half2 a, __half2 b, float c) {
#ifdef HAS_FDOT2
    half2v av, bv;
    __builtin_memcpy(&av, &a, 4);
    __builtin_memcpy(&bv, &b, 4);
    return __builtin_amdgcn_fdot2(av, bv, c, false);
#else
    float2 af = __half22float2(a), bf = __half22float2(b);
    return fmaf(af.y, bf.y, fmaf(af.x, bf.x, c));
#endif
}

static __device__ __forceinline__ float selu_f(float x) {
    const float scale = 1.0507009873554805f;
    const float alpha = 1.6732632423543772f;
    return x > 0.f ? scale * x : scale * alpha * (__expf(x) - 1.f);
}

// quad_perm DPP helpers
static __device__ __forceinline__ int pb0(int v) {   // [0,0,2,2] pair-bcast even
    return __builtin_amdgcn_mov_dpp(v, 0xA0, 0xf, 0xf, true);
}
static __device__ __forceinline__ int pb1(int v) {   // [1,1,3,3] pair-bcast odd
    return __builtin_amdgcn_mov_dpp(v, 0xF5, 0xf, 0xf, true);
}
static __device__ __forceinline__ float pswap(float x) {  // [1,0,3,2] pair swap
    return __int_as_float(__builtin_amdgcn_mov_dpp(__float_as_int(x), 0xB1, 0xf, 0xf, true));
}
static __device__ __forceinline__ float qx2f(float x) {   // [2,3,0,1] xor-2 swap
    return __int_as_float(__builtin_amdgcn_mov_dpp(__float_as_int(x), 0x4E, 0xf, 0xf, true));
}
static __device__ __forceinline__ __half2 h2pswap(__half2 v) {
    int i; __builtin_memcpy(&i, &v, 4);
    i = __builtin_amdgcn_mov_dpp(i, 0xB1, 0xf, 0xf, true);
    __half2 r; __builtin_memcpy(&r, &i, 4);
    return r;
}
static __device__ __forceinline__ __half2 h2qx2(__half2 v) {
    int i; __builtin_memcpy(&i, &v, 4);
    i = __builtin_amdgcn_mov_dpp(i, 0x4E, 0xf, 0xf, true);
    __half2 r; __builtin_memcpy(&r, &i, 4);
    return r;
}

static __device__ __forceinline__ void acc_add(__half2& a0, __half2& a1,
                                               __half2& a2, __half2& a3, H2x4 v) {
    a0 = __hadd2(a0, v.x); a1 = __hadd2(a1, v.y);
    a2 = __hadd2(a2, v.z); a3 = __hadd2(a3, v.w);
}

// ============================ CSR build (round-7) ===========================

__global__ void k_hist(const int* __restrict__ dst, int* __restrict__ MT,
                       int e, int nb) {
    __shared__ int hist[NBMAX];
    for (int t = threadIdx.x; t < nb; t += 256) hist[t] = 0;
    __syncthreads();
    int chunk = (e + NBLK - 1) / NBLK;
    int lo = blockIdx.x * chunk, hi = min(e, lo + chunk);
    for (int i = lo + threadIdx.x; i < hi; i += 256)
        atomicAdd(&hist[dst[i] >> 8], 1);
    __syncthreads();
    for (int t = threadIdx.x; t < nb; t += 256)
        MT[t * NBLK + blockIdx.x] = hist[t];
}

__global__ void k_cscan(int* __restrict__ MT, int* __restrict__ tot, int nb) {
    int k = blockIdx.x;
    int lane = threadIdx.x;  // 64
    int carry = 0;
    #pragma unroll
    for (int r = 0; r < NBLK; r += 64) {
        int v = MT[k * NBLK + r + lane];
        int inc = v;
        #pragma unroll
        for (int d = 1; d < 64; d <<= 1) {
            int w = __shfl_up(inc, d, 64);
            if (lane >= d) inc += w;
        }
        MT[k * NBLK + r + lane] = carry + inc - v;
        carry += __shfl(inc, 63, 64);
    }
    if (lane == 0) tot[k] = carry;
}

__global__ void k_bscan(const int* __restrict__ tot, int* __restrict__ base,
                        int* __restrict__ rp, int nb, int e, int n) {
    __shared__ int s[512];
    int t = threadIdx.x;
    int v = (t < nb) ? tot[t] : 0;
    s[t] = v;
    __syncthreads();
    #pragma unroll
    for (int d = 1; d < 512; d <<= 1) {
        int w = (t >= d) ? s[t - d] : 0;
        __syncthreads();
        s[t] += w;
        __syncthreads();
    }
    if (t < nb) base[t] = s[t] - v;
    if (t == nb - 1) base[nb] = s[t];
    if (t == 0) rp[n] = e;
}

__global__ void k_scatter(const int* __restrict__ src, const int* __restrict__ dst,
                          const int* __restrict__ MT, const int* __restrict__ base,
                          uint_t* __restrict__ pairs, int e, int nb) {
    __shared__ int cur[NBMAX];
    for (int t = threadIdx.x; t < nb; t += 256)
        cur[t] = base[t] + MT[t * NBLK + blockIdx.x];
    __syncthreads();
    int chunk = (e + NBLK - 1) / NBLK;
    int lo = blockIdx.x * chunk, hi = min(e, lo + chunk);
    for (int i = lo + threadIdx.x; i < hi; i += 256) {
        int d = dst[i];
        int pos = atomicAdd(&cur[d >> 8], 1);
        pairs[pos] = (uint_t)src[i] | ((uint_t)(d & 255) << 24);
    }
}

__global__ void k_build(const uint_t* __restrict__ pairs, const int* __restrict__ base,
                        int* __restrict__ rp, int* __restrict__ esrc, int n) {
    int k = blockIdx.x;
    int bb = base[k], be = base[k + 1];
    __shared__ int cnt[256], cur[256], stmp[256];
    int t = threadIdx.x;
    cnt[t] = 0;
    __syncthreads();
    for (int i = bb + t; i < be; i += 256)
        atomicAdd(&cnt[pairs[i] >> 24], 1);
    __syncthreads();
    int v = cnt[t];
    stmp[t] = v;
    __syncthreads();
    #pragma unroll
    for (int d = 1; d < 256; d <<= 1) {
        int w = (t >= d) ? stmp[t - d] : 0;
        __syncthreads();
        stmp[t] += w;
        __syncthreads();
    }
    int excl = stmp[t] - v;
    int nd = k * 256 + t;
    if (nd < n) rp[nd] = bb + excl;
    cur[t] = bb + excl;
    __syncthreads();
    for (int i = bb + t; i < be; i += 256) {
        uint_t p = pairs[i];
        int pos = atomicAdd(&cur[p >> 24], 1);
        esrc[pos] = (int)(p & 0xFFFFFFu);
    }
}

// ============================ network kernels ===============================

// block 0: 2 lanes/node (unchanged from round 12).
__global__ __launch_bounds__(256) void k_b0g(
    const float* __restrict__ x, const int* __restrict__ rp,
    const int* __restrict__ esrc,
    const float* __restrict__ W1, const float* __restrict__ b1,
    const float* __restrict__ W2, const float* __restrict__ b2,
    const float* __restrict__ W1next,
    __half2* __restrict__ hout, __half2* __restrict__ gout, int n) {
    __shared__ __align__(16) float sW1[16], sb1v[16], sW2[512], sb2v[32], sWn[512];
    if (threadIdx.x < 16) { sW1[threadIdx.x] = W1[threadIdx.x]; sb1v[threadIdx.x] = b1[threadIdx.x]; }
    for (int t = threadIdx.x; t < 512; t += 256) { sW2[t] = W2[t]; sWn[t] = W1next[t]; }
    if (threadIdx.x < 32) sb2v[threadIdx.x] = b2[threadIdx.x];
    __syncthreads();
    const int lane2 = threadIdx.x & 1;
    const int node = blockIdx.x * 128 + (threadIdx.x >> 1);
    if (node >= n) return;

    const int b = rp[node];
    const int deg = rp[node + 1] - b;
    const int half = deg >> 1;
    const int lo = lane2 ? half : 0;
    const int hi = lane2 ? deg : half;
    float a = lane2 ? 0.f : x[node];
    int j = lo;
    for (; j + 4 <= hi; j += 4) {
        int s0 = esrc[b + j], s1 = esrc[b + j + 1],
            s2 = esrc[b + j + 2], s3 = esrc[b + j + 3];
        float v0 = x[s0], v1 = x[s1], v2 = x[s2], v3 = x[s3];
        a += (v0 + v1) + (v2 + v3);
    }
    for (; j < hi; ++j) a += x[esrc[b + j]];
    a += pswap(a);

    float u[16];
    #pragma unroll
    for (int k = 0; k < 16; ++k) u[k] = selu_f(fmaf(a, sW1[k], sb1v[k]));

    const int jb = lane2 * 16;
    float row[16];
    #pragma unroll
    for (int q = 0; q < 16; ++q) row[q] = sb2v[jb + q];
    #pragma unroll
    for (int k = 0; k < 16; ++k) {
        const float4 w0 = *(const float4*)&sW2[k * 32 + jb];
        const float4 w1 = *(const float4*)&sW2[k * 32 + jb + 4];
        const float4 w2 = *(const float4*)&sW2[k * 32 + jb + 8];
        const float4 w3 = *(const float4*)&sW2[k * 32 + jb + 12];
        float uk = u[k];
        row[0]  = fmaf(uk, w0.x, row[0]);  row[1]  = fmaf(uk, w0.y, row[1]);
        row[2]  = fmaf(uk, w0.z, row[2]);  row[3]  = fmaf(uk, w0.w, row[3]);
        row[4]  = fmaf(uk, w1.x, row[4]);  row[5]  = fmaf(uk, w1.y, row[5]);
        row[6]  = fmaf(uk, w1.z, row[6]);  row[7]  = fmaf(uk, w1.w, row[7]);
        row[8]  = fmaf(uk, w2.x, row[8]);  row[9]  = fmaf(uk, w2.y, row[9]);
        row[10] = fmaf(uk, w2.z, row[10]); row[11] = fmaf(uk, w2.w, row[11]);
        row[12] = fmaf(uk, w3.x, row[12]); row[13] = fmaf(uk, w3.y, row[13]);
        row[14] = fmaf(uk, w3.z, row[14]); row[15] = fmaf(uk, w3.w, row[15]);
    }
    H2x4 o0, o1;
    o0.x = __floats2half2_rn(row[0], row[1]);   o0.y = __floats2half2_rn(row[2], row[3]);
    o0.z = __floats2half2_rn(row[4], row[5]);   o0.w = __floats2half2_rn(row[6], row[7]);
    o1.x = __floats2half2_rn(row[8], row[9]);   o1.y = __floats2half2_rn(row[10], row[11]);
    o1.z = __floats2half2_rn(row[12], row[13]); o1.w = __floats2half2_rn(row[14], row[15]);
    ((H2x4*)hout)[node * 4 + lane2 * 2]     = o0;
    ((H2x4*)hout)[node * 4 + lane2 * 2 + 1] = o1;

    float gp[16];
    #pragma unroll
    for (int k = 0; k < 16; ++k) gp[k] = 0.f;
    #pragma unroll
    for (int q = 0; q < 16; ++q) {
        const float4 w0 = *(const float4*)&sWn[(jb + q) * 16];
        const float4 w1 = *(const float4*)&sWn[(jb + q) * 16 + 4];
        const float4 w2 = *(const float4*)&sWn[(jb + q) * 16 + 8];
        const float4 w3 = *(const float4*)&sWn[(jb + q) * 16 + 12];
        float vq = row[q];
        gp[0]  = fmaf(vq, w0.x, gp[0]);  gp[1]  = fmaf(vq, w0.y, gp[1]);
        gp[2]  = fmaf(vq, w0.z, gp[2]);  gp[3]  = fmaf(vq, w0.w, gp[3]);
        gp[4]  = fmaf(vq, w1.x, gp[4]);  gp[5]  = fmaf(vq, w1.y, gp[5]);
        gp[6]  = fmaf(vq, w1.z, gp[6]);  gp[7]  = fmaf(vq, w1.w, gp[7]);
        gp[8]  = fmaf(vq, w2.x, gp[8]);  gp[9]  = fmaf(vq, w2.y, gp[9]);
        gp[10] = fmaf(vq, w2.z, gp[10]); gp[11] = fmaf(vq, w2.w, gp[11]);
        gp[12] = fmaf(vq, w3.x, gp[12]); gp[13] = fmaf(vq, w3.y, gp[13]);
        gp[14] = fmaf(vq, w3.z, gp[14]); gp[15] = fmaf(vq, w3.w, gp[15]);
    }
    float r[8];
    #pragma unroll
    for (int i = 0; i < 8; ++i) {
        float lo_ = gp[i]     + pswap(gp[i]);
        float hi_ = gp[8 + i] + pswap(gp[8 + i]);
        r[i] = lane2 ? hi_ : lo_;
    }
    H2x4 gv;
    gv.x = __floats2half2_rn(r[0], r[1]); gv.y = __floats2half2_rn(r[2], r[3]);
    gv.z = __floats2half2_rn(r[4], r[5]); gv.w = __floats2half2_rn(r[6], r[7]);
    ((H2x4*)gout)[node * 2 + lane2] = gv;
}

// mid blocks: 4 lanes/node, f16-dot MLP/projection, <=64-VGPR target.
// sW2h layout (stride 9 vs 8: breaks the 4-way bank conflict across lane4):
//   sW2h[j*9 + kp] = (W2[2kp][j], W2[2kp+1][j])     j in [0,32), kp in [0,8)
// sWnh layout: sWnh[k*16 + qp] = (Wn[2qp][k], Wn[2qp+1][k])  k,qp in [0,16)
template<int MODE>
__global__ __launch_bounds__(256, 8) void k_gmid(
    const __half2* __restrict__ gin, const __half2* __restrict__ hin,
    const int* __restrict__ rp, const int* __restrict__ esrc,
    const float* __restrict__ W2, const float* __restrict__ b1,
    const float* __restrict__ b2, const float* __restrict__ Wnext,
    __half2* __restrict__ hout, __half2* __restrict__ gout,
    float* __restrict__ zout, int n) {
    __shared__ __half2 sW2h[288];
    __shared__ __half2 sWnh[256];
    __shared__ float sb1[16], sb2[32], sWl[32];
    {
        const int t = threadIdx.x;
        const int j = t >> 3, kp = t & 7;
        sW2h[j * 9 + kp] = __floats2half2_rn(W2[(2 * kp) * 32 + j],
                                             W2[(2 * kp + 1) * 32 + j]);
        if (MODE == 0) {
            const int k = t >> 4, qp = t & 15;
            sWnh[k * 16 + qp] = __floats2half2_rn(Wnext[(2 * qp) * 16 + k],
                                                  Wnext[(2 * qp + 1) * 16 + k]);
        } else if (t < 32) {
            sWl[t] = Wnext[t];
        }
        if (t < 16) sb1[t] = b1[t];
        else if (t < 48) sb2[t - 16] = b2[t - 16];
    }
    __syncthreads();

    const int lane4 = threadIdx.x & 3;
    const int c = lane4 & 1;       // which 16B half of the 32B g row
    const int p = lane4 >> 1;      // which 8-edge sub-chunk of each 16
    const int node = blockIdx.x * 64 + (threadIdx.x >> 2);
    if (node >= n) return;

    const H2x4* grows = (const H2x4*)gin;
    const int ZR = n;   // zero pad row (memset at launch)
    // p=0 lanes init from self row; p=1 lanes init from zero row (no select)
    H2x4 ai = grows[(p ? ZR : node) * 2 + c];
    __half2 a0 = ai.x, a1 = ai.y, a2 = ai.z, a3 = ai.w;

    const int b = rp[node];
    const int deg = rp[node + 1] - b;
    for (int j0 = 0; j0 < deg; j0 += 16) {
        int lo = j0 + 8 * p;
        int m = deg - lo; m = m < 0 ? 0 : (m > 8 ? 8 : m);
        int i0 = lo + c,     i1 = lo + 2 + c, i2 = lo + 4 + c, i3 = lo + 6 + c;
        i0 = i0 < deg ? i0 : 0; i1 = i1 < deg ? i1 : 0;
        i2 = i2 < deg ? i2 : 0; i3 = i3 < deg ? i3 : 0;
        int e0 = esrc[b + i0], e1 = esrc[b + i1], e2 = esrc[b + i2], e3 = esrc[b + i3];
        int s0 = pb0(e0), s1 = pb1(e0), s2 = pb0(e1), s3 = pb1(e1);
        int s4 = pb0(e2), s5 = pb1(e2), s6 = pb0(e3), s7 = pb1(e3);
        s0 = 0 < m ? s0 : ZR; s1 = 1 < m ? s1 : ZR;
        s2 = 2 < m ? s2 : ZR; s3 = 3 < m ? s3 : ZR;
        s4 = 4 < m ? s4 : ZR; s5 = 5 < m ? s5 : ZR;
        s6 = 6 < m ? s6 : ZR; s7 = 7 < m ? s7 : ZR;
        H2x4 v0 = grows[s0 * 2 + c];
        H2x4 v1 = grows[s1 * 2 + c];
        H2x4 v2 = grows[s2 * 2 + c];
        H2x4 v3 = grows[s3 * 2 + c];
        H2x4 v4 = grows[s4 * 2 + c];
        H2x4 v5 = grows[s5 * 2 + c];
        H2x4 v6 = grows[s6 * 2 + c];
        H2x4 v7 = grows[s7 * 2 + c];
        acc_add(a0, a1, a2, a3, v0);
        acc_add(a0, a1, a2, a3, v1);
        acc_add(a0, a1, a2, a3, v2);
        acc_add(a0, a1, a2, a3, v3);
        acc_add(a0, a1, a2, a3, v4);
        acc_add(a0, a1, a2, a3, v5);
        acc_add(a0, a1, a2, a3, v6);
        acc_add(a0, a1, a2, a3, v7);
    }
    // combine the two edge-half partials (lane xor 2)
    a0 = __hadd2(a0, h2qx2(a0)); a1 = __hadd2(a1, h2qx2(a1));
    a2 = __hadd2(a2, h2qx2(a2)); a3 = __hadd2(a3, h2qx2(a3));

    // u = selu(acc + b1) for this lane's 8 hidden channels -> packed f16
    float2 f0 = __half22float2(a0), f1 = __half22float2(a1),
           f2 = __half22float2(a2), f3 = __half22float2(a3);
    const int kb = c * 8;
    __half2 own[4];
    own[0] = __floats2half2_rn(selu_f(f0.x + sb1[kb + 0]), selu_f(f0.y + sb1[kb + 1]));
    own[1] = __floats2half2_rn(selu_f(f1.x + sb1[kb + 2]), selu_f(f1.y + sb1[kb + 3]));
    own[2] = __floats2half2_rn(selu_f(f2.x + sb1[kb + 4]), selu_f(f2.y + sb1[kb + 5]));
    own[3] = __floats2half2_rn(selu_f(f3.x + sb1[kb + 6]), selu_f(f3.y + sb1[kb + 7]));

    // exchange with pair partner -> all 16 hidden values as 8 f16 pairs
    __half2 ua2[8];
    #pragma unroll
    for (int i = 0; i < 4; ++i) {
        __half2 o_ = h2pswap(own[i]);
        ua2[i]     = c ? o_     : own[i];
        ua2[4 + i] = c ? own[i] : o_;
    }

    // residual + bias, then MLP via dot2 over the 8 hidden pairs
    const int jb = lane4 * 8;   // this lane's 8 output channels
    H2x4 h0 = ((const H2x4*)hin)[node * 4 + lane4];
    float2 g0 = __half22float2(h0.x), g1 = __half22float2(h0.y),
           g2 = __half22float2(h0.z), g3 = __half22float2(h0.w);
    float o[8] = {g0.x, g0.y, g1.x, g1.y, g2.x, g2.y, g3.x, g3.y};
    #pragma unroll
    for (int q = 0; q < 8; ++q) {
        float acc = o[q] + sb2[jb + q];
        const __half2* wr = &sW2h[(jb + q) * 9];
        #pragma unroll
        for (int kp = 0; kp < 8; ++kp) acc = dot2(ua2[kp], wr[kp], acc);
        o[q] = acc;
    }

    // pack output row (needed for h store AND as f16 input to projection)
    H2x4 ov;
    ov.x = __floats2half2_rn(o[0], o[1]); ov.y = __floats2half2_rn(o[2], o[3]);
    ov.z = __floats2half2_rn(o[4], o[5]); ov.w = __floats2half2_rn(o[6], o[7]);

    if (MODE == 0) {
        ((H2x4*)hout)[node * 4 + lane4] = ov;

        // fused projection: partial over this lane's 4 q-pairs via dot2
        const int qb = lane4 * 4;
        float gp[16];
        #pragma unroll
        for (int k = 0; k < 16; ++k) {
            const __half2* wk = &sWnh[k * 16 + qb];
            float acc = dot2(ov.x, wk[0], 0.f);
            acc = dot2(ov.y, wk[1], acc);
            acc = dot2(ov.z, wk[2], acc);
            acc = dot2(ov.w, wk[3], acc);
            gp[k] = acc;
        }
        // distributed quad reduce: pair (keep c-half), xor2 (keep p-quarter)
        float r[8];
        #pragma unroll
        for (int i = 0; i < 8; ++i) {
            float lo_ = gp[i]     + pswap(gp[i]);
            float hi_ = gp[8 + i] + pswap(gp[8 + i]);
            r[i] = c ? hi_ : lo_;
        }
        float rr[4];
        #pragma unroll
        for (int i = 0; i < 4; ++i) {
            float lo_ = r[i]     + qx2f(r[i]);
            float hi_ = r[4 + i] + qx2f(r[4 + i]);
            rr[i] = p ? hi_ : lo_;
        }
        H2x2 gv;
        gv.x = __floats2half2_rn(rr[0], rr[1]);
        gv.y = __floats2half2_rn(rr[2], rr[3]);
        ((H2x2*)gout)[node * 4 + c * 2 + p] = gv;
    } else {
        float zp = 0.f;
        #pragma unroll
        for (int q = 0; q < 8; ++q) zp = fmaf(o[q], sWl[jb + q], zp);
        zp += pswap(zp);
        zp += qx2f(zp);
        if (lane4 == 0) zout[node] = zp;
    }
}

// last gather: 2 lanes/node, halved edge list (unchanged)
__global__ void k_gz(const float* __restrict__ z, const int* __restrict__ rp,
                     const int* __restrict__ esrc, float* __restrict__ out, int n) {
    const int lane2 = threadIdx.x & 1;
    const int node = blockIdx.x * 128 + (threadIdx.x >> 1);
    if (node >= n) return;
    const int b = rp[node];
    const int deg = rp[node + 1] - b;
    const int half = deg >> 1;
    const int lo = lane2 ? half : 0;
    const int hi = lane2 ? deg : half;
    float acc = lane2 ? 0.f : z[node];
    int j = lo;
    for (; j + 4 <= hi; j += 4) {
        int s0 = esrc[b + j], s1 = esrc[b + j + 1],
            s2 = esrc[b + j + 2], s3 = esrc[b + j + 3];
        float z0 = z[s0], z1 = z[s1], z2 = z[s2], z3 = z[s3];
        acc += (z0 + z1) + (z2 + z3);
    }
    for (; j < hi; ++j) acc += z[esrc[b + j]];
    acc += pswap(acc);
    if (lane2 == 0) out[node] = acc;
}

// ---------------------------------------------------------------------------

extern "C" void kernel_launch(void* const* d_in, const int* in_sizes, int n_in,
                              void* d_out, int out_size, void* d_ws, size_t ws_size,
                              hipStream_t stream) {
    const float* x    = (const float*)d_in[0];
    const int*   ei   = (const int*)d_in[1];
    const float* W1_0 = (const float*)d_in[2];
    const float* b1_0 = (const float*)d_in[3];
    const float* W2_0 = (const float*)d_in[4];
    const float* b2_0 = (const float*)d_in[5];
    const float* W1m  = (const float*)d_in[6];
    const float* b1m  = (const float*)d_in[7];
    const float* W2m  = (const float*)d_in[8];
    const float* b2m  = (const float*)d_in[9];
    const float* Wl   = (const float*)d_in[10];

    const int n = in_sizes[0];      // 100000 nodes
    const int e = in_sizes[1] / 2;  // 1.6M edges
    const int* srcp = ei;
    const int* dstp = ei + e;
    const int nb = (n + 255) >> 8;

    char* ws = (char*)d_ws;
    size_t off = 0;
    auto alloc = [&](size_t bytes) -> char* {
        char* p = ws + off;
        off += (bytes + 255) & ~size_t(255);
        return p;
    };
    __half2* hP   = (__half2*)alloc((size_t)n * 32 * 2);
    __half2* hQ   = (__half2*)alloc((size_t)n * 32 * 2);
    __half2* gA   = (__half2*)alloc((size_t)(n + 1) * 16 * 2);  // +1 zero pad row
    __half2* gB   = (__half2*)alloc((size_t)(n + 1) * 16 * 2);
    float*   z    = (float*)alloc((size_t)n * 4);
    int*     rp   = (int*)alloc((size_t)(n + 1) * 4);
    int*     esrc = (int*)alloc((size_t)e * 4);
    uint_t*  pairs= (uint_t*)alloc((size_t)e * 4);
    int*     MT   = (int*)alloc((size_t)NBMAX * NBLK * 4);
    int*     base = (int*)alloc((size_t)(NBMAX + 1) * 4);
    int*     tot  = (int*)alloc((size_t)NBMAX * 4);
    (void)ws_size;

    const int B = 256;
    const int gN = (n + B - 1) / B;
    const int g2 = (n + 127) / 128;   // 2 lanes/node kernels
    const int g4 = (n + 63) / 64;     // 4 lanes/node kernels

    // zero the pad rows (row n of gA/gB): 16 f16 = 8 __half2 = 32 bytes
    hipMemsetAsync(gA + (size_t)n * 8, 0, 32, stream);
    hipMemsetAsync(gB + (size_t)n * 8, 0, 32, stream);

    // --- CSR build ---
    k_hist<<<NBLK, B, 0, stream>>>(dstp, MT, e, nb);
    k_cscan<<<nb, 64, 0, stream>>>(MT, tot, nb);
    k_bscan<<<1, 512, 0, stream>>>(tot, base, rp, nb, e, n);
    k_scatter<<<NBLK, B, 0, stream>>>(srcp, dstp, MT, base, pairs, e, nb);
    k_build<<<nb, B, 0, stream>>>(pairs, base, rp, esrc, n);

    // --- block 0 (+ fused g1) ---
    k_b0g<<<g2, B, 0, stream>>>(x, rp, esrc, W1_0, b1_0, W2_0, b2_0,
                                W1m /* W1[0] */, hP, gA, n);

    // --- blocks 1..8 ---
    __half2* A = hP;  __half2* Bf = hQ;
    __half2* gin = gA; __half2* gnx = gB;
    for (int i = 0; i < 8; ++i) {
        if (i < 7) {
            k_gmid<0><<<g4, B, 0, stream>>>(gin, A, rp, esrc,
                                            W2m + i * 512, b1m + i * 16,
                                            b2m + i * 32, W1m + (i + 1) * 512,
                                            Bf, gnx, nullptr, n);
        } else {
            k_gmid<1><<<g4, B, 0, stream>>>(gin, A, rp, esrc,
                                            W2m + i * 512, b1m + i * 16,
                                            b2m + i * 32, Wl,
                                            Bf, nullptr, z, n);
        }
        __half2* t = A; A = Bf; Bf = t;
        __half2* tg = gin; gin = gnx; gnx = tg;
    }

    // --- block 9: gather of z ---
    k_gz<<<g2, B, 0, stream>>>(z, rp, esrc, (float*)d_out, n);
}